// Round 8
// baseline (259.636 us; speedup 1.0000x reference)
//
#include <hip/hip_runtime.h>
#include <hip/hip_bf16.h>
#include <math.h>

// Problem constants (B=1)
#define T_DIM 2048
#define D_DIM 2048
#define N_HEADS 16
#define K_HEADS 8
#define H_DIM 128
#define WINDOW_SZ 1024
#define SOFT_CAP 50.0f
#define Q_SCALE 0.08838834764831845f   // 1/sqrt(128)
#define LN_BASE 9.210340371976184f     // ln(10000)

typedef __hip_bfloat16 bf16;
typedef __attribute__((ext_vector_type(8))) short short8;
typedef __attribute__((ext_vector_type(4))) float floatx4;

static __device__ __forceinline__ bf16 f2b(float v) { return __float2bfloat16(v); }
static __device__ __forceinline__ float b2f(bf16 v) { return __bfloat162float(v); }

// ---------------------------------------------------------------------------
// Fused prep, coalesced-write transposes. 1D grid:
//   [0, 4096)    : qkv weight transpose (32 mats, [2048 d][128 h] -> WT_qkv[h][d])
//   [4096, 6144) : out weight transpose (16 mats, [128 h][2048 d] -> WT_out[d][n*128+h])
//   [6144, 8192) : x fp32 -> bf16 copy
// Transpose tile: read [64 r][32 c] (128 B row chunks), LDS [c][r] pad 65,
// write [32 c-rows][64 r] as short8 (8 rows x 128 B contiguous per inst).
// ---------------------------------------------------------------------------
__global__ __launch_bounds__(256) void prep_k(
    const float* __restrict__ x, const float* __restrict__ qk,
    const float* __restrict__ kvk, const float* __restrict__ ok,
    bf16* __restrict__ xb, bf16* __restrict__ WT_qkv, bf16* __restrict__ WT_out)
{
    __shared__ float tile[32][65];
    const int b = blockIdx.x;
    const int tid = threadIdx.x;

    if (b < 6144) {
        const float* src; bf16* dst;
        int S, Dst, r0, c0;
        size_t doff;
        if (b < 4096) {
            const int z = b >> 7, rem = b & 127;
            r0 = (rem >> 2) * 64;          // over D (2048)
            c0 = (rem & 3) * 32;           // over H (128)
            src = (z < 16) ? qk + (size_t)z * D_DIM * H_DIM
                           : kvk + (size_t)(z - 16) * D_DIM * H_DIM;
            S = H_DIM;
            dst = WT_qkv + (size_t)z * 128 * 2048;
            Dst = 2048; doff = 0;
        } else {
            const int b2 = b - 4096;
            const int z = b2 >> 7, rem = b2 & 127;
            r0 = (rem >> 6) * 64;          // over H (128)
            c0 = (rem & 63) * 32;          // over D (2048)
            src = ok + (size_t)z * H_DIM * D_DIM;
            S = D_DIM;
            dst = WT_out;
            Dst = 2048; doff = (size_t)z * 128;   // column block n*128
        }
        // read: 2 float4 per thread, 8 rows x 128 B per wave-inst
#pragma unroll
        for (int half = 0; half < 2; ++half) {
            int f = tid + half * 256;          // 0..511
            int r = f >> 3, cq = f & 7;        // r 0..63, c = cq*4
            float4 v = *(const float4*)(src + (size_t)(r0 + r) * S + c0 + cq * 4);
            tile[cq * 4 + 0][r] = v.x;
            tile[cq * 4 + 1][r] = v.y;
            tile[cq * 4 + 2][r] = v.z;
            tile[cq * 4 + 3][r] = v.w;
        }
        __syncthreads();
        // write: thread = (c-row, r-octet) -> short8
        const int c = tid >> 3, rt = (tid & 7) * 8;
        bf16 o[8];
#pragma unroll
        for (int j = 0; j < 8; ++j) o[j] = f2b(tile[c][rt + j]);
        *(short8*)(dst + (size_t)(c0 + c) * Dst + doff + r0 + rt) = *(const short8*)o;
    } else {
        const size_t i = ((size_t)(b - 6144) * 256 + tid) * 8;
        float4 a = *(const float4*)(x + i);
        float4 bb = *(const float4*)(x + i + 4);
        bf16 o[8] = {f2b(a.x), f2b(a.y), f2b(a.z), f2b(a.w),
                     f2b(bb.x), f2b(bb.y), f2b(bb.z), f2b(bb.w)};
        *(short8*)(xb + i) = *(const short8*)o;
    }
}

// ---------------------------------------------------------------------------
// MFMA GEMM (m97 structure + XOR-swizzled LDS): C[M,N] = A[M,K] * BT[N,K]^T.
// 128x128 tile, BK=32, 4 waves 2x2, 4x4 mfma_f32_16x16x32_bf16 per wave.
// (used for qkv projection; round-6/7 verified)
// ---------------------------------------------------------------------------
template <typename CT>
__global__ __launch_bounds__(256) void mfma_gemm_k(
    const bf16* __restrict__ A, const bf16* __restrict__ BT,
    CT* __restrict__ C, int Ndim, int Kdim)
{
    __shared__ alignas(16) bf16 As[128 * 32];
    __shared__ alignas(16) bf16 Bs[128 * 32];

    const int tid  = threadIdx.x;
    const int lane = tid & 63;
    const int wave = tid >> 6;
    const int lo   = lane & 15;
    const int quad = lane >> 4;
    const int row0 = blockIdx.x * 128;
    const int col0 = blockIdx.y * 128;
    const int wm = (wave >> 1) * 64;
    const int wn = (wave & 1) * 64;

    const int lrow = lane >> 2;
    const int lcol = ((lane & 3) ^ ((lane >> 3) & 3)) * 8;
    const int swk  = (quad ^ ((lo >> 1) & 3)) * 8;

    floatx4 acc[4][4];
#pragma unroll
    for (int i = 0; i < 4; ++i)
#pragma unroll
        for (int j = 0; j < 4; ++j) acc[i][j] = (floatx4){0.f, 0.f, 0.f, 0.f};

    for (int k0 = 0; k0 < Kdim; k0 += 32) {
        __syncthreads();
#pragma unroll
        for (int i = 0; i < 2; ++i) {
            const int trow = wave * 32 + i * 16 + lrow;
            const bf16* ga = A  + (size_t)(row0 + trow) * Kdim + k0 + lcol;
            const bf16* gb = BT + (size_t)(col0 + trow) * Kdim + k0 + lcol;
            __builtin_amdgcn_global_load_lds(
                (const __attribute__((address_space(1))) void*)ga,
                (__attribute__((address_space(3))) void*)(As + (wave * 2 + i) * 512),
                16, 0, 0);
            __builtin_amdgcn_global_load_lds(
                (const __attribute__((address_space(1))) void*)gb,
                (__attribute__((address_space(3))) void*)(Bs + (wave * 2 + i) * 512),
                16, 0, 0);
        }
        __syncthreads();

        short8 af[4], bfr[4];
#pragma unroll
        for (int mt = 0; mt < 4; ++mt)
            af[mt] = *(const short8*)&As[(wm + mt * 16 + lo) * 32 + swk];
#pragma unroll
        for (int nt = 0; nt < 4; ++nt)
            bfr[nt] = *(const short8*)&Bs[(wn + nt * 16 + lo) * 32 + swk];
#pragma unroll
        for (int mt = 0; mt < 4; ++mt)
#pragma unroll
            for (int nt = 0; nt < 4; ++nt)
                acc[mt][nt] = __builtin_amdgcn_mfma_f32_16x16x32_bf16(
                    af[mt], bfr[nt], acc[mt][nt], 0, 0, 0);
    }

#pragma unroll
    for (int mt = 0; mt < 4; ++mt)
#pragma unroll
        for (int nt = 0; nt < 4; ++nt)
#pragma unroll
            for (int r = 0; r < 4; ++r) {
                int rr = row0 + wm + mt * 16 + quad * 4 + r;
                int cc = col0 + wn + nt * 16 + lo;
                float v = acc[mt][nt][r];
                if constexpr (__is_same(CT, bf16)) C[(size_t)rr * Ndim + cc] = f2b(v);
                else                               C[(size_t)rr * Ndim + cc] = v;
            }
}

// ---------------------------------------------------------------------------
// N-split MFMA GEMM for the out projection: 128x64 tile, full K, fp32 out.
// grid (M/128, N/64) = (16,32) = 512 blocks = 2/CU -> no partials, no add pass.
// Per wave: 4x2 acc tiles; staging 2 A-segments + 1 B-segment per wave.
// ---------------------------------------------------------------------------
__global__ __launch_bounds__(256) void mfma_gemm_n64_k(
    const bf16* __restrict__ A, const bf16* __restrict__ BT,
    float* __restrict__ C, int Ndim, int Kdim)
{
    __shared__ alignas(16) bf16 As[128 * 32];
    __shared__ alignas(16) bf16 Bs[64 * 32];

    const int tid  = threadIdx.x;
    const int lane = tid & 63;
    const int wave = tid >> 6;
    const int lo   = lane & 15;
    const int quad = lane >> 4;
    const int row0 = blockIdx.x * 128;
    const int col0 = blockIdx.y * 64;
    const int wm = (wave >> 1) * 64;
    const int wn = (wave & 1) * 32;

    const int lrow = lane >> 2;
    const int lcol = ((lane & 3) ^ ((lane >> 3) & 3)) * 8;
    const int swk  = (quad ^ ((lo >> 1) & 3)) * 8;

    floatx4 acc[4][2];
#pragma unroll
    for (int i = 0; i < 4; ++i)
#pragma unroll
        for (int j = 0; j < 2; ++j) acc[i][j] = (floatx4){0.f, 0.f, 0.f, 0.f};

    for (int k0 = 0; k0 < Kdim; k0 += 32) {
        __syncthreads();
#pragma unroll
        for (int i = 0; i < 2; ++i) {
            const int trow = wave * 32 + i * 16 + lrow;
            const bf16* ga = A + (size_t)(row0 + trow) * Kdim + k0 + lcol;
            __builtin_amdgcn_global_load_lds(
                (const __attribute__((address_space(1))) void*)ga,
                (__attribute__((address_space(3))) void*)(As + (wave * 2 + i) * 512),
                16, 0, 0);
        }
        {
            const int trow = wave * 16 + lrow;
            const bf16* gb = BT + (size_t)(col0 + trow) * Kdim + k0 + lcol;
            __builtin_amdgcn_global_load_lds(
                (const __attribute__((address_space(1))) void*)gb,
                (__attribute__((address_space(3))) void*)(Bs + wave * 512),
                16, 0, 0);
        }
        __syncthreads();

        short8 af[4], bfr[2];
#pragma unroll
        for (int mt = 0; mt < 4; ++mt)
            af[mt] = *(const short8*)&As[(wm + mt * 16 + lo) * 32 + swk];
#pragma unroll
        for (int nt = 0; nt < 2; ++nt)
            bfr[nt] = *(const short8*)&Bs[(wn + nt * 16 + lo) * 32 + swk];
#pragma unroll
        for (int mt = 0; mt < 4; ++mt)
#pragma unroll
            for (int nt = 0; nt < 2; ++nt)
                acc[mt][nt] = __builtin_amdgcn_mfma_f32_16x16x32_bf16(
                    af[mt], bfr[nt], acc[mt][nt], 0, 0, 0);
    }

#pragma unroll
    for (int mt = 0; mt < 4; ++mt)
#pragma unroll
        for (int nt = 0; nt < 2; ++nt)
#pragma unroll
            for (int r = 0; r < 4; ++r) {
                int rr = row0 + wm + mt * 16 + quad * 4 + r;
                int cc = col0 + wn + nt * 16 + lo;
                C[(size_t)rr * Ndim + cc] = acc[mt][nt][r];
            }
}

// ---------------------------------------------------------------------------
// RoPE on K only (q-rope fused into attn). 512 pairs per t.
// ---------------------------------------------------------------------------
__global__ __launch_bounds__(256) void rope_kk(bf16* __restrict__ qkvb,
                                               const int* __restrict__ segpos)
{
    const int t = blockIdx.x;
    const float pos = (float)segpos[t];
    bf16* rowp = qkvb + (size_t)t * 4096 + 2048;
#pragma unroll
    for (int it = 0; it < 2; ++it) {
        int p = threadIdx.x + it * 256;
        int hp = p & 63;
        bf16* buf = rowp + (p >> 6) * 128;
        float fraction = (float)hp * (1.0f / 64.0f);
        float inv_ts = __expf(-fraction * LN_BASE);
        float ang = pos * inv_ts;
        float sv, cv; __sincosf(ang, &sv, &cv);
        float first  = b2f(buf[hp]);
        float second = b2f(buf[hp + 64]);
        buf[hp]      = f2b(first * cv - second * sv);
        buf[hp + 64] = f2b(second * cv + first * sv);
    }
}

// ---------------------------------------------------------------------------
// Flash MFMA attention, fixed-m softmax (softcap bounds logits to ±50).
// Q-rope fused into the Q-fragment load. (round-6/7 verified)
// ---------------------------------------------------------------------------
__global__ __launch_bounds__(256) void attn_k(
    const bf16* __restrict__ qkvb, const int* __restrict__ segpos,
    bf16* __restrict__ ebuf)
{
    __shared__ alignas(16) bf16 Ks[2][32][136];
    __shared__ alignas(16) bf16 Vt[2][128][40];
    __shared__ alignas(16) bf16 Ps[4][16][40];

    const int t0 = blockIdx.x * 64;
    const int n  = blockIdx.y;
    const int kh = n >> 1;
    const int tid  = threadIdx.x;
    const int lane = tid & 63;
    const int wave = tid >> 6;
    const int lo   = lane & 15;
    const int quad = lane >> 4;
    const int twlo = t0 + wave * 16;

    short8 qf[4];
    {
        const int tq = twlo + lo;
        const float pos = (float)segpos[tq];
        const bf16* qp = qkvb + (size_t)tq * 4096 + n * 128;
        float qv[4][8];
#pragma unroll
        for (int kc = 0; kc < 4; ++kc) {
            short8 raw = *(const short8*)(qp + kc * 32 + quad * 8);
            const bf16* rb = (const bf16*)&raw;
#pragma unroll
            for (int j = 0; j < 8; ++j) qv[kc][j] = b2f(rb[j]);
        }
#pragma unroll
        for (int kc = 0; kc < 2; ++kc)
#pragma unroll
            for (int j = 0; j < 8; ++j) {
                int hp = kc * 32 + quad * 8 + j;
                float ang = pos * __expf(-(float)hp * (1.0f / 64.0f) * LN_BASE);
                float sv, cv; __sincosf(ang, &sv, &cv);
                float first = qv[kc][j], second = qv[kc + 2][j];
                qv[kc][j]     = (first * cv - second * sv) * Q_SCALE;
                qv[kc + 2][j] = (second * cv + first * sv) * Q_SCALE;
            }
#pragma unroll
        for (int kc = 0; kc < 4; ++kc) {
            bf16 o[8];
#pragma unroll
            for (int j = 0; j < 8; ++j) o[j] = f2b(qv[kc][j]);
            qf[kc] = *(const short8*)o;
        }
    }

    floatx4 O[8];
#pragma unroll
    for (int i = 0; i < 8; ++i) O[i] = (floatx4){0.f, 0.f, 0.f, 0.f};
    float l_acc[4] = {0.f, 0.f, 0.f, 0.f};

    const int key_a = tid >> 3,      hd_a = (tid & 7) * 16;
    const int kp2   = (tid & 15) * 2, hd_b = (tid >> 4) * 8;

    const int s_start = (t0 > 1023) ? (t0 - 1024) : 0;
    const int nch = (t0 + 63 - s_start) / 32 + 1;

    const bf16* kg = qkvb + 2048 + kh * 128;
    const bf16* vg = qkvb + 3072 + kh * 128;

    short8 kr0 = *(const short8*)(kg + (size_t)(s_start + key_a) * 4096 + hd_a);
    short8 kr1 = *(const short8*)(kg + (size_t)(s_start + key_a) * 4096 + hd_a + 8);
    short8 vr0 = *(const short8*)(vg + (size_t)(s_start + kp2) * 4096 + hd_b);
    short8 vr1 = *(const short8*)(vg + (size_t)(s_start + kp2 + 1) * 4096 + hd_b);

    for (int c = 0; c < nch; ++c) {
        const int base = s_start + c * 32;
        const int buf = c & 1;

        *(short8*)&Ks[buf][key_a][hd_a]     = kr0;
        *(short8*)&Ks[buf][key_a][hd_a + 8] = kr1;
#pragma unroll
        for (int i = 0; i < 8; ++i) {
            unsigned pk = (unsigned)(unsigned short)vr0[i] |
                          ((unsigned)(unsigned short)vr1[i] << 16);
            *(unsigned*)&Vt[buf][hd_b + i][kp2] = pk;
        }
        if (c + 1 < nch) {
            const int nb = base + 32;
            kr0 = *(const short8*)(kg + (size_t)(nb + key_a) * 4096 + hd_a);
            kr1 = *(const short8*)(kg + (size_t)(nb + key_a) * 4096 + hd_a + 8);
            vr0 = *(const short8*)(vg + (size_t)(nb + kp2) * 4096 + hd_b);
            vr1 = *(const short8*)(vg + (size_t)(nb + kp2 + 1) * 4096 + hd_b);
        }
        __syncthreads();

        const int dbase = twlo - base;
        if (dbase >= -15 && dbase <= 1054) {
            floatx4 S0 = (floatx4){0.f, 0.f, 0.f, 0.f};
            floatx4 S1 = (floatx4){0.f, 0.f, 0.f, 0.f};
#pragma unroll
            for (int kc = 0; kc < 4; ++kc) {
                short8 b0 = *(const short8*)&Ks[buf][lo][kc * 32 + quad * 8];
                short8 b1 = *(const short8*)&Ks[buf][16 + lo][kc * 32 + quad * 8];
                S0 = __builtin_amdgcn_mfma_f32_16x16x32_bf16(qf[kc], b0, S0, 0, 0, 0);
                S1 = __builtin_amdgcn_mfma_f32_16x16x32_bf16(qf[kc], b1, S1, 0, 0, 0);
            }
            short8 vfrag[8];
#pragma unroll
            for (int nt = 0; nt < 8; ++nt)
                vfrag[nt] = *(const short8*)&Vt[buf][nt * 16 + lo][quad * 8];

            const bool need_mask = !(dbase >= 31 && dbase <= 1008);
            const int dq = dbase + quad * 4 - lo;
            float lg[2][4];
#pragma unroll
            for (int tau = 0; tau < 2; ++tau) {
#pragma unroll
                for (int r = 0; r < 4; ++r) {
                    float sv = (tau == 0) ? S0[r] : S1[r];
                    float ax = fabsf(sv) * (2.0f / SOFT_CAP);
                    float e2 = __expf(-ax);
                    float th = (1.0f - e2) * __builtin_amdgcn_rcpf(1.0f + e2);
                    float l  = copysignf(SOFT_CAP * th, sv);
                    float p  = __expf(l);
                    if (need_mask) {
                        int d = dq + r - tau * 16;
                        if ((unsigned)d > 1023u) p = 0.f;
                    }
                    lg[tau][r] = p;
                }
            }
#pragma unroll
            for (int r = 0; r < 4; ++r) l_acc[r] += lg[0][r] + lg[1][r];

#pragma unroll
            for (int tau = 0; tau < 2; ++tau)
#pragma unroll
                for (int r = 0; r < 4; ++r)
                    Ps[wave][quad * 4 + r][tau * 16 + lo] = f2b(lg[tau][r]);

            short8 pfrag = *(const short8*)&Ps[wave][lo][quad * 8];
#pragma unroll
            for (int nt = 0; nt < 8; ++nt)
                O[nt] = __builtin_amdgcn_mfma_f32_16x16x32_bf16(pfrag, vfrag[nt], O[nt], 0, 0, 0);
        }
    }

#pragma unroll
    for (int xm = 1; xm < 16; xm <<= 1)
#pragma unroll
        for (int r = 0; r < 4; ++r) l_acc[r] += __shfl_xor(l_acc[r], xm, 64);
    float invl[4];
#pragma unroll
    for (int r = 0; r < 4; ++r) invl[r] = 1.0f / l_acc[r];

#pragma unroll
    for (int nt = 0; nt < 8; ++nt)
#pragma unroll
        for (int r = 0; r < 4; ++r) {
            int t = twlo + quad * 4 + r;
            ebuf[(size_t)t * 2048 + n * 128 + nt * 16 + lo] = f2b(O[nt][r] * invl[r]);
        }
}

// ---------------------------------------------------------------------------
extern "C" void kernel_launch(void* const* d_in, const int* in_sizes, int n_in,
                              void* d_out, int out_size, void* d_ws, size_t ws_size,
                              hipStream_t stream)
{
    const float* x   = (const float*)d_in[0];
    const int*  segp = (const int*)d_in[1];
    // d_in[2] = attn_mask (bool) -- redundant with causal+window predicate, ignored
    const float* qk  = (const float*)d_in[3];
    const float* kvk = (const float*)d_in[4];
    const float* ok  = (const float*)d_in[5];

    // Workspace (48 MB): xb(0..8, aliased by ebuf) | WT_qkv(8..24) | WT_out(24..32) | qkvb(32..48)
    bf16* xb     = (bf16*)d_ws;
    bf16* ebuf   = xb;
    bf16* WT_qkv = xb + (size_t)4 * 1024 * 1024;
    bf16* WT_out = WT_qkv + (size_t)8 * 1024 * 1024;
    bf16* qkvb   = WT_out + (size_t)4 * 1024 * 1024;
    float* outp  = (float*)d_out;

    prep_k<<<dim3(8192), dim3(256), 0, stream>>>(x, qk, kvk, ok, xb, WT_qkv, WT_out);
    mfma_gemm_k<bf16><<<dim3(16, 32), dim3(256), 0, stream>>>(
        xb, WT_qkv, qkvb, 4096, 2048);
    rope_kk<<<dim3(T_DIM), dim3(256), 0, stream>>>(qkvb, segp);
    attn_k<<<dim3(T_DIM / 64, N_HEADS), dim3(256), 0, stream>>>(qkvb, segp, ebuf);
    mfma_gemm_n64_k<<<dim3(16, 32), dim3(256), 0, stream>>>(
        ebuf, WT_out, outp, 2048, 2048);
}